// Round 1
// baseline (659.131 us; speedup 1.0000x reference)
//
#include <hip/hip_runtime.h>
#include <hip/hip_cooperative_groups.h>

namespace cg = cooperative_groups;

#define N_NEUR 256
#define N_EDGE 1024
#define BATCH  128
#define HWDIM  28
#define IMG    784            // 28*28
#define NPIX   (BATCH * IMG)  // 100352
#define FCH    200
#define NCLS   10
#define INF_W  0x3fffffff

// Grid chosen so gridDim.x * blockDim.x == NPIX exactly (392*256 = 100352):
// every thread owns one fixed pixel (b,y,x) for the whole conv phase.
#define GRID_BLOCKS 392

__global__ __launch_bounds__(256, 2)
void net_kernel(const float* __restrict__ x, const int* __restrict__ src,
                const int* __restrict__ tgt,
                const float* __restrict__ conv_w, const float* __restrict__ conv_b,
                const float* __restrict__ fc1_w, const float* __restrict__ fc1_b,
                const float* __restrict__ fc2_w, const float* __restrict__ fc2_b,
                float* __restrict__ dout, float* __restrict__ ws,
                int cmax, int dlast)
{
    cg::grid_group grid = cg::this_grid();
    const int tid   = threadIdx.x;
    const int gtid  = blockIdx.x * blockDim.x + tid;   // < NPIX

    // ---- workspace layout ----
    float* outAct = ws;                                   // [256][NPIX]
    float* hidden = ws + (size_t)N_NEUR * NPIX;           // [128][200]
    int*   ib     = (int*)(hidden + BATCH * FCH);
    int*   ideg      = ib;          // [256]
    int*   iwave     = ib + 256;    // [256]
    int*   inact     = ib + 512;    // [256]
    int*   waveOff   = ib + 768;    // [320]
    int*   waveNodes = ib + 1088;   // [256]
    int*   iidx      = ib + 1344;         // [256*cmax] in-list (edge order)
    int*   iact      = iidx + 256 * cmax; // [256*cmax] packed (u | c<<8), active only

    // ================= schedule (block 0 only) =================
    if (blockIdx.x == 0) {
        const int i = tid;  // neuron id, 256 threads
        {
            int d = 0;
            for (int e = 0; e < N_EDGE; ++e) {
                if (tgt[e] == i) { iidx[i * cmax + d] = src[e]; ++d; }
            }
            ideg[i]  = d;
            iwave[i] = (i == 0) ? 0 : INF_W;
        }
        __syncthreads();
        // BFS waves from neuron 0; stop once neuron 255 is assigned.
        __shared__ int s_done;
        for (int w = 0; w < 300; ++w) {
            if (tid == 0) s_done = (iwave[N_NEUR - 1] != INF_W);
            __syncthreads();
            if (s_done) break;
            for (int e = tid; e < N_EDGE; e += 256) {
                int s = src[e], t = tgt[e];
                if (iwave[s] == w && iwave[t] == INF_W) iwave[t] = w + 1;
            }
            __syncthreads();
        }
        // Compact active channels: channel c (source u) contributes iff wave[u] < wave[v].
        {
            const int wv = iwave[i];
            const int dv = ideg[i];
            int na = 0;
            for (int c = 0; c < dv; ++c) {
                int u = iidx[i * cmax + c];
                if (iwave[u] < wv) { iact[i * cmax + na] = u | (c << 8); ++na; }
            }
            inact[i] = na;
        }
        __syncthreads();
        // Parallel build of per-wave node lists (neuron 255 excluded: FC node).
        {
            const int Wl = iwave[N_NEUR - 1];
            if (tid <= Wl + 1) {
                int c = 0;
                for (int v = 0; v < N_NEUR - 1; ++v) if (iwave[v] < tid) ++c;
                waveOff[tid] = c;
            }
            const int v = tid;
            if (v < N_NEUR - 1 && iwave[v] != INF_W) {
                const int wv = iwave[v];
                int pos = 0;
                for (int v2 = 0; v2 < N_NEUR - 1; ++v2) {
                    int w2 = iwave[v2];
                    if (w2 < wv || (w2 == wv && v2 < v)) ++pos;
                }
                waveNodes[pos] = v;
            }
        }
    }
    grid.sync();

    const int W = iwave[N_NEUR - 1];

    // Fixed pixel for this thread.
    const int p   = gtid;
    const int b   = p / IMG;
    const int rem = p - b * IMG;
    const int y   = rem / HWDIM;
    const int xx  = rem - y * HWDIM;

    // ================= conv waves =================
    for (int w = 0; w <= W; ++w) {
        const int off = waveOff[w];
        const int cnt = waveOff[w + 1] - off;
        for (int ni = 0; ni < cnt; ++ni) {
            const int v = waveNodes[off + ni];
            float acc = conv_b[v];
            if (v == 0) {
                // neuron 0: input image, channel 0 weights
                const float* in = x + b * IMG;
                const float* wv = conv_w;
                #pragma unroll
                for (int dy = 0; dy < 5; ++dy) {
                    int yy = y + dy - 2;
                    if ((unsigned)yy >= HWDIM) continue;
                    const float* row = in + yy * HWDIM;
                    #pragma unroll
                    for (int dx = 0; dx < 5; ++dx) {
                        int xc = xx + dx - 2;
                        if ((unsigned)xc < HWDIM)
                            acc = fmaf(row[xc], wv[dy * 5 + dx], acc);
                    }
                }
            } else {
                const int  na = inact[v];
                const int* av = iact + v * cmax;
                for (int a = 0; a < na; ++a) {
                    const int pk = av[a];
                    const int u  = pk & 255;
                    const int c  = pk >> 8;
                    const float* in = outAct + (size_t)u * NPIX + b * IMG;
                    const float* wv = conv_w + ((size_t)v * cmax + c) * 25;
                    #pragma unroll
                    for (int dy = 0; dy < 5; ++dy) {
                        int yy = y + dy - 2;
                        if ((unsigned)yy >= HWDIM) continue;
                        const float* row = in + yy * HWDIM;
                        #pragma unroll
                        for (int dx = 0; dx < 5; ++dx) {
                            int xc = xx + dx - 2;
                            if ((unsigned)xc < HWDIM)
                                acc = fmaf(row[xc], wv[dy * 5 + dx], acc);
                        }
                    }
                }
            }
            outAct[(size_t)v * NPIX + p] = fmaxf(acc, 0.0f);
        }
        grid.sync();
    }

    // ================= FC1 (hidden = relu(comp @ fc1_w.T + b1)) =================
    {
        const int  naL = inact[N_NEUR - 1];
        const int* av  = iact + (N_NEUR - 1) * cmax;
        const int idx = gtid;               // gsize == NPIX > 25600, single pass
        if (idx < FCH * BATCH) {
            const int bb = idx & (BATCH - 1);
            const int h  = idx >> 7;
            float acc = fc1_b[h];
            for (int a = 0; a < naL; ++a) {
                const int pk = av[a];
                const int u  = pk & 255;
                const int k  = pk >> 8;
                const float* in = outAct + (size_t)u * NPIX + bb * IMG;
                const float* wr = fc1_w + (size_t)h * ((size_t)dlast * IMG) + (size_t)k * IMG;
                float s = 0.0f;
                for (int j = 0; j < IMG; ++j) s = fmaf(in[j], wr[j], s);
                acc += s;
            }
            hidden[bb * FCH + h] = fmaxf(acc, 0.0f);
        }
    }
    grid.sync();

    // ================= FC2 + log_softmax =================
    if (gtid < BATCH) {
        const int bb = gtid;
        float lg[NCLS];
        float m = -1e30f;
        const float* hr = hidden + bb * FCH;
        #pragma unroll
        for (int c = 0; c < NCLS; ++c) {
            float acc = fc2_b[c];
            const float* wr = fc2_w + c * FCH;
            for (int h = 0; h < FCH; ++h) acc = fmaf(hr[h], wr[h], acc);
            lg[c] = acc;
            m = fmaxf(m, acc);
        }
        float s = 0.0f;
        #pragma unroll
        for (int c = 0; c < NCLS; ++c) s += expf(lg[c] - m);
        const float ls = m + logf(s);
        #pragma unroll
        for (int c = 0; c < NCLS; ++c) dout[bb * NCLS + c] = lg[c] - ls;
    }
}

extern "C" void kernel_launch(void* const* d_in, const int* in_sizes, int n_in,
                              void* d_out, int out_size, void* d_ws, size_t ws_size,
                              hipStream_t stream) {
    const float* x      = (const float*)d_in[0];
    const int*   src    = (const int*)d_in[1];
    const int*   tgt    = (const int*)d_in[2];
    const float* conv_w = (const float*)d_in[3];
    const float* conv_b = (const float*)d_in[4];
    const float* fc1_w  = (const float*)d_in[5];
    const float* fc1_b  = (const float*)d_in[6];
    const float* fc2_w  = (const float*)d_in[7];
    const float* fc2_b  = (const float*)d_in[8];
    float* out = (float*)d_out;
    float* ws  = (float*)d_ws;

    int cmax  = in_sizes[3] / (N_NEUR * 25);   // conv_w: [256,1,cmax,5,5]
    int dlast = in_sizes[5] / (FCH * IMG);     // fc1_w:  [200, dlast*784]

    void* kargs[] = { (void*)&x, (void*)&src, (void*)&tgt, (void*)&conv_w, (void*)&conv_b,
                      (void*)&fc1_w, (void*)&fc1_b, (void*)&fc2_w, (void*)&fc2_b,
                      (void*)&out, (void*)&ws, (void*)&cmax, (void*)&dlast };
    hipLaunchCooperativeKernel((void*)net_kernel, dim3(GRID_BLOCKS), dim3(256),
                               kargs, 0, stream);
}